// Round 1
// baseline (103.582 us; speedup 1.0000x reference)
//
#include <hip/hip_runtime.h>

// CIN layer fused kernel.
// Shapes: x0 (1024,32,64) f32, xk (1024,32,64) f32, W (64,1,32,32) f32, bias (64) f32
// out (1024,64,64) f32.
//
// Derivation: out[b,n,w] = bias[n] + sum_{r,j} x0[b, w&31, 2r+h] * xk[b, j, 2r+h] * W[n,r,j]
// with h = w>>5.  Factored: G[n,r,h] = sum_j W[n,r,j]*xk[b,j,2r+h];
//                 out[b,n,w] = bias[n] + sum_r x0T[2r+h][w&31] * G[n,r,h].

constexpr int T0  = 32;
constexpr int F   = 64;
constexpr int NF  = 64;
constexpr int TSK = 32;

constexpr int ST0 = 36;  // x0T row stride (floats): pad to spread banks, keeps 16B align for t0%4==0
constexpr int GST = 65;  // G row stride (floats): +1 pad -> scalar accesses 2-way max (free)

__global__ __launch_bounds__(256, 2)
void cin_fused(const float* __restrict__ x0,
               const float* __restrict__ xk,
               const float* __restrict__ W,
               const float* __restrict__ bias,
               float* __restrict__ out)
{
    __shared__ __align__(16) float xk_lds[T0 * F];   // [j][fi] linear (reads are wave-broadcast)
    __shared__ __align__(16) float x0T[F * ST0];     // [fi][t], padded stride 36
    __shared__ __align__(16) float Gs[NF * GST];     // [n][h*32 + r], padded stride 65

    const int b   = blockIdx.x;
    const int tid = threadIdx.x;

    // ---------------- Phase 1: stage ----------------
    {
        // xk: linear copy, 2048 floats = 512 float4, fully coalesced, conflict-free LDS writes
        const float4* srck = reinterpret_cast<const float4*>(xk + (size_t)b * T0 * F);
        float4*       dstk = reinterpret_cast<float4*>(xk_lds);
        dstk[tid]       = srck[tid];
        dstk[tid + 256] = srck[tid + 256];

        // x0: coalesced float4 global reads, transposed scalar LDS writes ([fi][t])
        const float4* src0 = reinterpret_cast<const float4*>(x0 + (size_t)b * T0 * F);
        const float4 a0 = src0[tid];         // flat words tid*4        -> t = tid>>4,      fi0=(tid&15)*4
        const float4 a1 = src0[tid + 256];   // flat words tid*4 + 1024 -> t = (tid>>4)+16, same fi0
        const int t   = tid >> 4;
        const int fi0 = (tid & 15) * 4;
        x0T[(fi0 + 0) * ST0 + t]      = a0.x;
        x0T[(fi0 + 1) * ST0 + t]      = a0.y;
        x0T[(fi0 + 2) * ST0 + t]      = a0.z;
        x0T[(fi0 + 3) * ST0 + t]      = a0.w;
        x0T[(fi0 + 0) * ST0 + t + 16] = a1.x;
        x0T[(fi0 + 1) * ST0 + t + 16] = a1.y;
        x0T[(fi0 + 2) * ST0 + t + 16] = a1.z;
        x0T[(fi0 + 3) * ST0 + t + 16] = a1.w;
    }
    __syncthreads();

    // ---------------- Phase 2: G[n][h*32+r] = sum_j W[n,r,j] * xk[j][2r+h] ----------------
    {
        const int n = tid & 63;            // wave covers all n
        const int g = tid >> 6;            // r in [g*8, g*8+8)
        const float*  Wn  = W + (size_t)n * T0 * TSK;
        const float2* xk2 = reinterpret_cast<const float2*>(xk_lds);  // xk2[j*32 + r] = (xk[j][2r], xk[j][2r+1])
        for (int rr = 0; rr < 8; ++rr) {
            const int r = g * 8 + rr;
            const float4* wrow = reinterpret_cast<const float4*>(Wn + r * TSK);
            float g0 = 0.f, g1 = 0.f;
            #pragma unroll
            for (int jj = 0; jj < 8; ++jj) {
                const float4 w4 = wrow[jj];                   // W[n,r,4jj..4jj+3] (L2-resident)
                const float2 k0 = xk2[(jj * 4 + 0) * 32 + r]; // broadcast reads (same addr across wave)
                const float2 k1 = xk2[(jj * 4 + 1) * 32 + r];
                const float2 k2 = xk2[(jj * 4 + 2) * 32 + r];
                const float2 k3 = xk2[(jj * 4 + 3) * 32 + r];
                g0 = fmaf(w4.x, k0.x, g0); g1 = fmaf(w4.x, k0.y, g1);
                g0 = fmaf(w4.y, k1.x, g0); g1 = fmaf(w4.y, k1.y, g1);
                g0 = fmaf(w4.z, k2.x, g0); g1 = fmaf(w4.z, k2.y, g1);
                g0 = fmaf(w4.w, k3.x, g0); g1 = fmaf(w4.w, k3.y, g1);
            }
            Gs[n * GST + r]      = g0;   // h=0   (bank = (n+r)%32 -> 2-way max, free)
            Gs[n * GST + 32 + r] = g1;   // h=1
        }
    }
    __syncthreads();

    // ---------------- Phase 3: out[b,n,w] = bias[n] + sum_r x0T[2r+h][t] * G[n][h*32+r] ----------------
    {
        const int w0 = (tid & 15) * 4;   // 0,4,...,60  (never straddles h boundary)
        const int n0 = (tid >> 4) * 4;   // 0,4,...,60
        const int h  = w0 >> 5;
        const int t0 = w0 & 31;

        float acc[4][4];
        #pragma unroll
        for (int e = 0; e < 4; ++e) {
            const float bv = bias[n0 + e];
            acc[e][0] = bv; acc[e][1] = bv; acc[e][2] = bv; acc[e][3] = bv;
        }

        #pragma unroll 4
        for (int r = 0; r < 32; ++r) {
            const float4 xv = *reinterpret_cast<const float4*>(&x0T[(2 * r + h) * ST0 + t0]);
            #pragma unroll
            for (int e = 0; e < 4; ++e) {
                const float gv = Gs[(n0 + e) * GST + h * 32 + r];
                acc[e][0] = fmaf(gv, xv.x, acc[e][0]);
                acc[e][1] = fmaf(gv, xv.y, acc[e][1]);
                acc[e][2] = fmaf(gv, xv.z, acc[e][2]);
                acc[e][3] = fmaf(gv, xv.w, acc[e][3]);
            }
        }

        float* ob = out + (size_t)b * NF * F;
        #pragma unroll
        for (int e = 0; e < 4; ++e) {
            *reinterpret_cast<float4*>(&ob[(n0 + e) * F + w0]) =
                make_float4(acc[e][0], acc[e][1], acc[e][2], acc[e][3]);
        }
    }
}

extern "C" void kernel_launch(void* const* d_in, const int* in_sizes, int n_in,
                              void* d_out, int out_size, void* d_ws, size_t ws_size,
                              hipStream_t stream) {
    const float* x0   = (const float*)d_in[0];
    const float* xk   = (const float*)d_in[1];
    const float* W    = (const float*)d_in[2];
    const float* bias = (const float*)d_in[3];
    float* out = (float*)d_out;

    cin_fused<<<dim3(1024), dim3(256), 0, stream>>>(x0, xk, W, bias, out);
}

// Round 2
// 96.290 us; speedup vs baseline: 1.0757x; 1.0757x over previous
//
#include <hip/hip_runtime.h>

// CIN layer fused kernel, round 2: W register-resident, 4 batches/block.
//
// out[b,n,w] = bias[n] + sum_{r,j} x0[b, w&31, 2r+h] * xk[b, j, 2r+h] * W[n,r,j],  h = w>>5
// Factored:  G[n, h, r] = sum_j W[n,r,j] * xk[b, j, 2r+h]
//            out[b,n,w] = bias[n] + sum_r x0T[2r+h][w&31] * G[n, h, r]
//
// Block = 1024 threads (16 waves), grid = 256 (1 block/CU). Thread (n=tid&63,
// g=tid>>6) holds W[n][2g..2g+1][:] in 64 VGPRs, loaded once, reused across
// the block's 4 batches. Per batch: stage (1 float4/thread, reg-prefetched one
// batch ahead), phase B (G, W-from-regs + broadcast LDS xk), phase C (out).

constexpr int ST0 = 36;  // x0T row stride (words); with t-XOR swizzle -> <=2-way banks
constexpr int GST = 65;  // G row stride: scalar access 2-way max (free)

__global__ __launch_bounds__(1024, 4)
void cin_fused(const float* __restrict__ x0,
               const float* __restrict__ xk,
               const float* __restrict__ W,
               const float* __restrict__ bias,
               float* __restrict__ out)
{
    __shared__ __align__(16) float xk_lds[2][32 * 64];  // [j][fi] linear
    __shared__ __align__(16) float x0T[2][64 * ST0];    // [fi][t^swz], padded
    __shared__ __align__(16) float Gs[64 * GST];        // [n][h*32 + r], padded

    const int tid = threadIdx.x;
    const int b0  = blockIdx.x * 4;

    // ---- W registers: thread (n, g) owns rows r0 = 2g, 2g+1 (one-time 4KB-stride read)
    const int n  = tid & 63;
    const int g  = tid >> 6;
    const int r0 = g * 2;

    float4 wr[16];  // wr[0..7] = W[n][r0][0..31], wr[8..15] = W[n][r0+1][0..31]
    {
        const float4* wp = reinterpret_cast<const float4*>(W + ((size_t)n * 32 + r0) * 32);
        #pragma unroll
        for (int q = 0; q < 16; ++q) wr[q] = wp[q];
    }
    const float bv = bias[tid >> 4];  // phase C: nc = tid>>4

    // ---- staging identity: threads 0..511 stage xk, 512..1023 stage x0 (transpose)
    const bool do_xk = tid < 512;
    const int  u     = do_xk ? tid : tid - 512;   // float4 index into the 2048-float slab
    const int  st_t  = u >> 4;                    // x0: source row t
    const int  st_f  = u & 15;                    // x0: fi0 = 4*st_f
    const int  st_ts = st_t ^ (4 * (st_f & 7));   // swizzled t (kills 8-way write conflict)

    // prefetch batch 0 into registers
    float4 sreg;
    {
        const float* src = do_xk ? (xk + (size_t)b0 * 2048) : (x0 + (size_t)b0 * 2048);
        sreg = reinterpret_cast<const float4*>(src)[u];
    }

    for (int k = 0; k < 4; ++k) {
        const int buf = k & 1;

        // ---- commit staged registers to LDS
        if (do_xk) {
            reinterpret_cast<float4*>(xk_lds[buf])[u] = sreg;  // linear, conflict-free
        } else {
            float* row = &x0T[buf][(4 * st_f) * ST0];
            row[0 * ST0 + st_ts] = sreg.x;
            row[1 * ST0 + st_ts] = sreg.y;
            row[2 * ST0 + st_ts] = sreg.z;
            row[3 * ST0 + st_ts] = sreg.w;
        }
        __syncthreads();

        // ---- prefetch next batch (hidden under phases B+C)
        if (k < 3) {
            const float* src = do_xk ? (xk + (size_t)(b0 + k + 1) * 2048)
                                     : (x0 + (size_t)(b0 + k + 1) * 2048);
            sreg = reinterpret_cast<const float4*>(src)[u];
        }

        // ---- phase B: G[n][h*32+r] for r in {r0, r0+1}
        {
            float g00 = 0.f, g01 = 0.f, g10 = 0.f, g11 = 0.f;
            const float4* xk4 = reinterpret_cast<const float4*>(xk_lds[buf]);
            #pragma unroll
            for (int jq = 0; jq < 8; ++jq) {
                // kv = xk[j][4g .. 4g+3] = ((r0,h0),(r0,h1),(r0+1,h0),(r0+1,h1)) — wave-broadcast
                const float4 k0 = xk4[(jq * 4 + 0) * 16 + g];
                const float4 k1 = xk4[(jq * 4 + 1) * 16 + g];
                const float4 k2 = xk4[(jq * 4 + 2) * 16 + g];
                const float4 k3 = xk4[(jq * 4 + 3) * 16 + g];
                const float4 w0v = wr[jq];       // W[n][r0][4jq..]
                const float4 w1v = wr[8 + jq];   // W[n][r0+1][4jq..]
                g00 = fmaf(w0v.x, k0.x, g00); g01 = fmaf(w0v.x, k0.y, g01);
                g10 = fmaf(w1v.x, k0.z, g10); g11 = fmaf(w1v.x, k0.w, g11);
                g00 = fmaf(w0v.y, k1.x, g00); g01 = fmaf(w0v.y, k1.y, g01);
                g10 = fmaf(w1v.y, k1.z, g10); g11 = fmaf(w1v.y, k1.w, g11);
                g00 = fmaf(w0v.z, k2.x, g00); g01 = fmaf(w0v.z, k2.y, g01);
                g10 = fmaf(w1v.z, k2.z, g10); g11 = fmaf(w1v.z, k2.w, g11);
                g00 = fmaf(w0v.w, k3.x, g00); g01 = fmaf(w0v.w, k3.y, g01);
                g10 = fmaf(w1v.w, k3.z, g10); g11 = fmaf(w1v.w, k3.w, g11);
            }
            Gs[n * GST + r0]          = g00;  // h=0
            Gs[n * GST + 32 + r0]     = g01;  // h=1
            Gs[n * GST + r0 + 1]      = g10;
            Gs[n * GST + 32 + r0 + 1] = g11;
        }
        __syncthreads();

        // ---- phase C: out[b, nc, w0..w0+3]
        {
            const int nc = tid >> 4;
            const int wq = tid & 15;
            const int w0 = wq * 4;
            const int h  = w0 >> 5;
            const int t0 = w0 & 31;
            float ax = bv, ay = bv, az = bv, aw = bv;
            #pragma unroll
            for (int r = 0; r < 32; ++r) {
                const int row = 2 * r + h;
                const int tsw = t0 ^ (4 * ((r >> 1) & 7));  // matches staging swizzle (fi>>2 = r>>1)
                const float4 xv = *reinterpret_cast<const float4*>(&x0T[buf][row * ST0 + tsw]);
                const float  gv = Gs[nc * GST + h * 32 + r];
                ax = fmaf(gv, xv.x, ax);
                ay = fmaf(gv, xv.y, ay);
                az = fmaf(gv, xv.z, az);
                aw = fmaf(gv, xv.w, aw);
            }
            // word offset nc*64 + w0 == tid*4 -> fully coalesced float4 store
            reinterpret_cast<float4*>(out + (size_t)(b0 + k) * 64 * 64)[tid] =
                make_float4(ax, ay, az, aw);
        }
        // no barrier needed here: next iteration's staging writes touch buf^1 only
    }
}

extern "C" void kernel_launch(void* const* d_in, const int* in_sizes, int n_in,
                              void* d_out, int out_size, void* d_ws, size_t ws_size,
                              hipStream_t stream) {
    const float* x0   = (const float*)d_in[0];
    const float* xk   = (const float*)d_in[1];
    const float* W    = (const float*)d_in[2];
    const float* bias = (const float*)d_in[3];
    float* out = (float*)d_out;

    cin_fused<<<dim3(256), dim3(1024), 0, stream>>>(x0, xk, W, bias, out);
}